// Round 6
// baseline (900.508 us; speedup 1.0000x reference)
//
#include <hip/hip_runtime.h>
#include <hip/hip_bf16.h>
#include <stdint.h>

typedef float f32x4 __attribute__((ext_vector_type(4)));
typedef short short8 __attribute__((ext_vector_type(8)));

#define C8 11.5415603f   // 8*log2(e)

static __device__ __forceinline__ unsigned short f2bf(float f) {
    union { float f; uint32_t u; } x; x.f = f;
    return (unsigned short)((x.u + 0x7FFFu + ((x.u >> 16) & 1u)) >> 16);  // RNE
}
static __device__ __forceinline__ uint32_t pk2(float a, float b) {
    float2 t; t.x = a; t.y = b;
    union { __hip_bfloat162 h; uint32_t u; } c;
    c.h = __float22bfloat162_rn(t);           // v_cvt_pk_bf16_f32
    return c.u;
}
// tanh(z) with arg = 2z*log2(e):  1 - 2/(1+exp2(arg))
static __device__ __forceinline__ float tanh_e2(float arg) {
    float E = __builtin_amdgcn_exp2f(arg);
    return __builtin_fmaf(-2.0f, __builtin_amdgcn_rcpf(E + 1.0f), 1.0f);
}

// LDS layout: 128-short (256B) rows, no pad. Bank conflicts avoided by XOR
// swizzle of the within-row BYTE offset with (row&7)<<4. All main-loop rows
// satisfy row&7 == j&7, so the read swizzle is per-lane constant.
__global__ __launch_bounds__(256, 2)
void mf_ising(const float* __restrict__ feat, const float* __restrict__ lf,
              const float* __restrict__ Jg, float* __restrict__ out) {
    __shared__ __align__(16) unsigned short JT[128 * 128];  // J^T bf16, diag 0 (32 KiB)
    __shared__ __align__(16) unsigned short SL[128 * 128];  // spins bf16      (32 KiB)

    const int tid  = threadIdx.x;
    const int wave = tid >> 6;
    const int lane = tid & 63;
    const int j    = lane & 15;
    const int g    = lane >> 4;
    const int sw   = (j & 7) << 4;   // swizzle for rows with row&7 == j&7

    // ---- stage J^T (bf16, diag 0), conflict-free swizzled writes, 64B-coalesced reads
    {
        const int il = lane & 15, kl = lane >> 4;
        const int ibase = wave * 32 + il;
        #pragma unroll 4
        for (int c = 0; c < 64; ++c) {
            int i = ibase + 16 * (c & 1);
            int k = kl + 4 * (c >> 1);
            float v = (i == k) ? 0.0f : Jg[k * 128 + i];
            JT[i * 128 + (((2 * k) ^ ((i & 7) << 4)) >> 1)] = f2bf(v);
        }
    }
    __syncthreads();   // JT ready; SL rows are wave-private -> no barriers in main loop

    const int rowBase = blockIdx.x * 128 + wave * 32;
    const int slRow   = wave * 32 + j;              // + jt*16

    // local field; rides the MFMA C-operand at kt==0
    f32x4 lfv[8];
    #pragma unroll
    for (int it = 0; it < 8; ++it)
        lfv[it] = *(const f32x4*)(lf + it * 16 + g * 4);

    // two independent row-tiles per wave: sreg[jt][it][r] = s[rowBase+jt*16+j][16it+4g+r]
    f32x4 sreg[2][8];
    #pragma unroll
    for (int jt = 0; jt < 2; ++jt) {
        const size_t row = (size_t)(rowBase + jt * 16 + j);
        #pragma unroll
        for (int it = 0; it < 8; ++it) {
            f32x4 fv = *(const f32x4*)(feat + row * 128 + it * 16 + g * 4);
            f32x4 s;
            #pragma unroll
            for (int r = 0; r < 4; ++r) s[r] = tanh_e2(0.28853901f * fv[r]); // tanh(0.1f)
            sreg[jt][it] = s;
        }
    }

    f32x4 acc[2][8];

    auto matvec = [&]() {
        // spins -> LDS bf16 (8B stores, swizzled, 2-way max = free)
        #pragma unroll
        for (int jt = 0; jt < 2; ++jt) {
            unsigned short* srow = &SL[(slRow + jt * 16) * 128];
            #pragma unroll
            for (int it = 0; it < 8; ++it) {
                uint2 v;
                v.x = pk2(sreg[jt][it][0], sreg[jt][it][1]);
                v.y = pk2(sreg[jt][it][2], sreg[jt][it][3]);
                *(uint2*)(srow + (((it * 32 + g * 8) ^ sw) >> 1)) = v;
            }
        }
        // C'[i][j] = lf[i] + sum_k J^T[i][k] s^T[k][j]; one J-frag feeds both tiles
        #pragma unroll
        for (int kt = 0; kt < 4; ++kt) {
            const int ro = ((kt * 64 + g * 16) ^ sw) >> 1;
            short8 b0 = *(const short8*)&SL[(slRow)      * 128 + ro];
            short8 b1 = *(const short8*)&SL[(slRow + 16) * 128 + ro];
            #pragma unroll
            for (int it = 0; it < 8; ++it) {
                short8 a = *(const short8*)&JT[(16 * it + j) * 128 + ro];
                if (kt == 0) {
                    acc[0][it] = __builtin_amdgcn_mfma_f32_16x16x32_bf16(a, b0, lfv[it], 0, 0, 0);
                    acc[1][it] = __builtin_amdgcn_mfma_f32_16x16x32_bf16(a, b1, lfv[it], 0, 0, 0);
                } else {
                    acc[0][it] = __builtin_amdgcn_mfma_f32_16x16x32_bf16(a, b0, acc[0][it], 0, 0, 0);
                    acc[1][it] = __builtin_amdgcn_mfma_f32_16x16x32_bf16(a, b1, acc[1][it], 0, 0, 0);
                }
            }
        }
    };

    #pragma unroll 1
    for (int t = 0; t < 25; ++t) {
        matvec();                                   // acc = lf + s@Jm (both tiles)
        #pragma unroll
        for (int jt = 0; jt < 2; ++jt) {
            #pragma unroll
            for (int it = 0; it < 8; ++it) {
                f32x4 s = sreg[jt][it], h = acc[jt][it];
                #pragma unroll
                for (int r = 0; r < 4; ++r) {
                    float E  = __builtin_amdgcn_exp2f(h[r] * C8);        // e^{8h}
                    float rc = __builtin_amdgcn_rcpf(E + 1.0f);
                    // s' = 0.7*tanh(4h) + 0.3*s = (0.3s + 0.7) - 1.4/(1+E)
                    s[r] = __builtin_fmaf(-1.4f, rc, __builtin_fmaf(0.3f, s[r], 0.7f));
                }
                sreg[jt][it] = s;
            }
        }
    }
    matvec();   // final h_eff in acc, final spins in sreg

    // ---- outputs (f32): spins [B,128] then free_energy [B,1]
    #pragma unroll
    for (int jt = 0; jt < 2; ++jt) {
        const size_t row = (size_t)(rowBase + jt * 16 + j);
        #pragma unroll
        for (int it = 0; it < 8; ++it)
            *(f32x4*)(out + row * 128 + it * 16 + g * 4) = sreg[jt][it];
    }
    #pragma unroll
    for (int jt = 0; jt < 2; ++jt) {
        float p = 0.0f;
        #pragma unroll
        for (int it = 0; it < 8; ++it) {
            #pragma unroll
            for (int r = 0; r < 4; ++r) {
                float y = 4.0f * acc[jt][it][r];
                float a = fabsf(y);
                float q = __builtin_amdgcn_exp2f(-2.88539008f * a);      // e^{-2|y|}
                p += a + 0.69314718f * __builtin_amdgcn_logf(1.0f + q);  // |y|+ln(1+q)
            }
        }
        p += __shfl_xor(p, 16, 64);
        p += __shfl_xor(p, 32, 64);   // sum over the 4 g-groups of this row
        if (lane < 16) {
            size_t row = (size_t)(rowBase + jt * 16 + j);
            out[(size_t)262144 * 128 + row] = -0.25f * p;
        }
    }
}

extern "C" void kernel_launch(void* const* d_in, const int* in_sizes, int n_in,
                              void* d_out, int out_size, void* d_ws, size_t ws_size,
                              hipStream_t stream) {
    const float* feat = (const float*)d_in[0];
    const float* lfld = (const float*)d_in[1];
    const float* Jg   = (const float*)d_in[2];
    float* out = (float*)d_out;
    (void)in_sizes; (void)n_in; (void)out_size; (void)d_ws; (void)ws_size;

    dim3 grid(2048), block(256);
    hipLaunchKernelGGL(mf_ising, grid, block, 0, stream, feat, lfld, Jg, out);
}

// Round 10
// 860.276 us; speedup vs baseline: 1.0468x; 1.0468x over previous
//
#include <hip/hip_runtime.h>
#include <hip/hip_bf16.h>
#include <stdint.h>

typedef float f32x4 __attribute__((ext_vector_type(4)));
typedef short short8 __attribute__((ext_vector_type(8)));

#define C8 11.5415603f   // 8*log2(e)

static __device__ __forceinline__ unsigned short f2bf(float f) {
    union { float f; uint32_t u; } x; x.f = f;
    return (unsigned short)((x.u + 0x7FFFu + ((x.u >> 16) & 1u)) >> 16);  // RNE
}
static __device__ __forceinline__ uint32_t pk2(float a, float b) {
    float2 t; t.x = a; t.y = b;
    union { __hip_bfloat162 h; uint32_t u; } c;
    c.h = __float22bfloat162_rn(t);           // v_cvt_pk_bf16_f32
    return c.u;
}
static __device__ __forceinline__ float bflo(uint32_t w) {   // low bf16 -> f32 (1 op)
    union { uint32_t u; float f; } x; x.u = w << 16; return x.f;
}
static __device__ __forceinline__ float bfhi(uint32_t w) {   // high bf16 -> f32 (1 op)
    union { uint32_t u; float f; } x; x.u = w & 0xFFFF0000u; return x.f;
}
// tanh(z) with arg = 2z*log2(e):  1 - 2/(1+exp2(arg))
static __device__ __forceinline__ float tanh_e2(float arg) {
    float E = __builtin_amdgcn_exp2f(arg);
    return __builtin_fmaf(-2.0f, __builtin_amdgcn_rcpf(E + 1.0f), 1.0f);
}

// LDS: 128-short (256B) rows, no pad; XOR swizzle of within-row BYTE offset
// with (row&7)<<4. All main-loop rows satisfy row&7 == j&7 -> per-lane const.
// Spin state lives as PACKED bf16 in registers (sp, 32 regs) to avoid the
// round-6 register spill (f32 sreg+acc+lfv > arch budget -> lfv spilled to
// scratch -> 1.3 GB HBM refill traffic).
__global__ __launch_bounds__(256, 2)
void mf_ising(const float* __restrict__ feat, const float* __restrict__ lf,
              const float* __restrict__ Jg, float* __restrict__ out) {
    __shared__ __align__(16) unsigned short JT[128 * 128];  // J^T bf16, diag 0 (32 KiB)
    __shared__ __align__(16) unsigned short SL[128 * 128];  // spins bf16      (32 KiB)

    const int tid  = threadIdx.x;
    const int wave = tid >> 6;
    const int lane = tid & 63;
    const int j    = lane & 15;
    const int g    = lane >> 4;
    const int sw   = (j & 7) << 4;

    // ---- stage J^T (bf16, diag 0); one-time cost
    {
        const int il = lane & 15, kl = lane >> 4;
        const int ibase = wave * 32 + il;
        #pragma unroll 4
        for (int c = 0; c < 64; ++c) {
            int i = ibase + 16 * (c & 1);
            int k = kl + 4 * (c >> 1);
            float v = (i == k) ? 0.0f : Jg[k * 128 + i];
            JT[i * 128 + (((2 * k) ^ ((i & 7) << 4)) >> 1)] = f2bf(v);
        }
    }

    const int rowBase = blockIdx.x * 128 + wave * 32;
    const int slRow   = wave * 32 + j;              // + jt*16

    // local field; rides the MFMA C-operand at kt==0
    f32x4 lfv[8];
    #pragma unroll
    for (int it = 0; it < 8; ++it)
        lfv[it] = *(const f32x4*)(lf + it * 16 + g * 4);

    // spins: PACKED bf16, sp[jt][it] = {pk(s0,s1), pk(s2,s3)} for
    // s[row=rowBase+jt*16+j][spin=16it+4g+{0..3}]. Also staged to SL.
    uint2 sp[2][8];
    #pragma unroll
    for (int jt = 0; jt < 2; ++jt) {
        const size_t row = (size_t)(rowBase + jt * 16 + j);
        unsigned short* srow = &SL[(slRow + jt * 16) * 128];
        #pragma unroll
        for (int it = 0; it < 8; ++it) {
            f32x4 fv = *(const f32x4*)(feat + row * 128 + it * 16 + g * 4);
            f32x4 s;
            #pragma unroll
            for (int r = 0; r < 4; ++r) s[r] = tanh_e2(0.28853901f * fv[r]); // tanh(0.1f)
            uint2 v; v.x = pk2(s[0], s[1]); v.y = pk2(s[2], s[3]);
            sp[jt][it] = v;
            *(uint2*)(srow + (((it * 32 + g * 8) ^ sw) >> 1)) = v;
        }
    }
    __syncthreads();   // JT ready; SL rows are wave-private -> no barriers after

    f32x4 acc[2][8];

    auto matvec = [&]() {   // reads SL (current spins), J from LDS; acc = lf + s@Jm
        #pragma unroll
        for (int kt = 0; kt < 4; ++kt) {
            const int ro = ((kt * 64 + g * 16) ^ sw) >> 1;
            short8 b0 = *(const short8*)&SL[(slRow)      * 128 + ro];
            short8 b1 = *(const short8*)&SL[(slRow + 16) * 128 + ro];
            #pragma unroll
            for (int it = 0; it < 8; ++it) {
                short8 a = *(const short8*)&JT[(16 * it + j) * 128 + ro];
                if (kt == 0) {
                    acc[0][it] = __builtin_amdgcn_mfma_f32_16x16x32_bf16(a, b0, lfv[it], 0, 0, 0);
                    acc[1][it] = __builtin_amdgcn_mfma_f32_16x16x32_bf16(a, b1, lfv[it], 0, 0, 0);
                } else {
                    acc[0][it] = __builtin_amdgcn_mfma_f32_16x16x32_bf16(a, b0, acc[0][it], 0, 0, 0);
                    acc[1][it] = __builtin_amdgcn_mfma_f32_16x16x32_bf16(a, b1, acc[1][it], 0, 0, 0);
                }
            }
        }
    };

    #pragma unroll 1
    for (int t = 0; t < 25; ++t) {
        matvec();
        // update: s' = 0.3*s + 0.7*tanh(4h) = (0.3s+0.7) - 1.4/(1+e^{8h});
        // unpack bf16 s_old (1 op/elem), repack (pk2 also feeds the LDS write)
        #pragma unroll
        for (int jt = 0; jt < 2; ++jt) {
            unsigned short* srow = &SL[(slRow + jt * 16) * 128];
            #pragma unroll
            for (int it = 0; it < 8; ++it) {
                uint2 w = sp[jt][it];
                f32x4 h = acc[jt][it];
                float so[4] = { bflo(w.x), bfhi(w.x), bflo(w.y), bfhi(w.y) };
                float sn[4];
                #pragma unroll
                for (int r = 0; r < 4; ++r) {
                    float E  = __builtin_amdgcn_exp2f(h[r] * C8);        // e^{8h}
                    float rc = __builtin_amdgcn_rcpf(E + 1.0f);
                    sn[r] = __builtin_fmaf(-1.4f, rc, __builtin_fmaf(0.3f, so[r], 0.7f));
                }
                uint2 v; v.x = pk2(sn[0], sn[1]); v.y = pk2(sn[2], sn[3]);
                sp[jt][it] = v;
                *(uint2*)(srow + (((it * 32 + g * 8) ^ sw) >> 1)) = v;
            }
        }
    }
    matvec();   // final h_eff in acc; final spins (bf16) in sp

    // ---- outputs (f32): spins [B,128] then free_energy [B,1]
    #pragma unroll
    for (int jt = 0; jt < 2; ++jt) {
        const size_t row = (size_t)(rowBase + jt * 16 + j);
        #pragma unroll
        for (int it = 0; it < 8; ++it) {
            uint2 w = sp[jt][it];
            f32x4 s; s[0] = bflo(w.x); s[1] = bfhi(w.x); s[2] = bflo(w.y); s[3] = bfhi(w.y);
            *(f32x4*)(out + row * 128 + it * 16 + g * 4) = s;
        }
    }
    #pragma unroll
    for (int jt = 0; jt < 2; ++jt) {
        float p = 0.0f;
        #pragma unroll
        for (int it = 0; it < 8; ++it) {
            #pragma unroll
            for (int r = 0; r < 4; ++r) {
                float y = 4.0f * acc[jt][it][r];
                float a = fabsf(y);
                float q = __builtin_amdgcn_exp2f(-2.88539008f * a);      // e^{-2|y|}
                p += a + 0.69314718f * __builtin_amdgcn_logf(1.0f + q);  // |y|+ln(1+q)
            }
        }
        p += __shfl_xor(p, 16, 64);
        p += __shfl_xor(p, 32, 64);   // sum over the 4 g-groups of this row
        if (lane < 16) {
            size_t row = (size_t)(rowBase + jt * 16 + j);
            out[(size_t)262144 * 128 + row] = -0.25f * p;
        }
    }
}

extern "C" void kernel_launch(void* const* d_in, const int* in_sizes, int n_in,
                              void* d_out, int out_size, void* d_ws, size_t ws_size,
                              hipStream_t stream) {
    const float* feat = (const float*)d_in[0];
    const float* lfld = (const float*)d_in[1];
    const float* Jg   = (const float*)d_in[2];
    float* out = (float*)d_out;
    (void)in_sizes; (void)n_in; (void)out_size; (void)d_ws; (void)ws_size;

    dim3 grid(2048), block(256);
    hipLaunchKernelGGL(mf_ising, grid, block, 0, stream, feat, lfld, Jg, out);
}